// Round 11
// baseline (66.898 us; speedup 1.0000x reference)
//
#include <hip/hip_runtime.h>
#include <hip/hip_fp16.h>

// Problem constants
#define NB 4      // batch
#define CI 256    // input channels
#define HH 64
#define WW 64
#define MC 64     // compressed channels
#define HS 128    // H*2
#define WS_ 128   // W*2
#define HW 4096   // HH*WW
// wpack: [n][sh:2][pix:4096][28] uints; each uint = half2 (q=2sh, q=2sh+1)

typedef __attribute__((ext_vector_type(8))) short short8v;   // 8 bf16 (4 VGPRs)
typedef __attribute__((ext_vector_type(4))) float floatx4;   // MFMA C/D

__device__ inline unsigned short f2bf(float f) {
  union { float f; unsigned u; } v; v.f = f;
  unsigned r = v.u + 0x7FFFu + ((v.u >> 16) & 1u);   // RNE
  return (unsigned short)(r >> 16);
}

// ---------------------------------------------------------------------------
// Prep: rearrange weights into MFMA A-fragment layout (bf16).  (unchanged)
// ---------------------------------------------------------------------------
__global__ __launch_bounds__(256) void prep_kernel(
    const float* __restrict__ w_comp, const float* __restrict__ w_enc,
    unsigned short* __restrict__ Aw1, unsigned short* __restrict__ Aw2) {
  int i = blockIdx.x * 256 + threadIdx.x;
  if (i < 16384) {                       // 8*64*32
    int kl = i & 31, o = (i >> 5) & 63, ks = i >> 11;
    Aw1[i] = f2bf(w_comp[o * 256 + ks * 32 + kl]);
  } else if (i < 16384 + 64512) {        // 18*112*32
    int j = i - 16384;
    int kl = j & 31, o = (j >> 5) % 112, ks = (j >> 5) / 112;
    int t = ks >> 1, m = (ks & 1) * 32 + kl;
    Aw2[j] = (o < 100) ? f2bf(w_enc[o * 576 + m * 9 + t]) : (unsigned short)0;
  }
}

// ---------------------------------------------------------------------------
// Kernel 1: 1x1 conv via MFMA, v3: LDS-staged COALESCED x reads.
// Block 512 thr, 32-px tile: stage x[256c][32px] via float4-along-pixels
// (128 B contiguous per channel), pack bf16 channel-pairs, ds_write_b32 to
// channel-last LDS [px][264]. 8 waves = 2 px-halves x 4 K-quarters (2 ks).
// B-frags now ds_read_b128 from LDS. pacc exchange as before.
// ---------------------------------------------------------------------------
__global__ __launch_bounds__(512, 1) void conv1x1_mfma(
    const float* __restrict__ x, const unsigned short* __restrict__ Aw1,
    const float* __restrict__ b_comp, unsigned short* __restrict__ comp_cl) {
  __shared__ unsigned short xs[32 * 264];   // [px][c], c-dim 256+8 pad
  __shared__ float pacc[2][64][49];
  int tid = threadIdx.x;
  int bid = blockIdx.x;                     // 512 blocks: n(4) x 128 tiles
  int n = bid >> 7;
  int px0 = (bid & 127) * 32;

  const float* xb = x + (size_t)n * CI * HW + px0;
  {
    int cpair = (tid >> 3) * 2;             // 0..126 even
    int p4 = (tid & 7) * 4;                 // 0..28
#pragma unroll
    for (int rr = 0; rr < 2; ++rr) {
      int c0 = rr * 128 + cpair;
      float4 va = *(const float4*)(xb + (size_t)c0 * HW + p4);
      float4 vb = *(const float4*)(xb + (size_t)(c0 + 1) * HW + p4);
      unsigned u0 = (unsigned)f2bf(va.x) | ((unsigned)f2bf(vb.x) << 16);
      unsigned u1 = (unsigned)f2bf(va.y) | ((unsigned)f2bf(vb.y) << 16);
      unsigned u2 = (unsigned)f2bf(va.z) | ((unsigned)f2bf(vb.z) << 16);
      unsigned u3 = (unsigned)f2bf(va.w) | ((unsigned)f2bf(vb.w) << 16);
      *(unsigned*)(xs + (p4 + 0) * 264 + c0) = u0;
      *(unsigned*)(xs + (p4 + 1) * 264 + c0) = u1;
      *(unsigned*)(xs + (p4 + 2) * 264 + c0) = u2;
      *(unsigned*)(xs + (p4 + 3) * 264 + c0) = u3;
    }
  }
  __syncthreads();

  int wid = tid >> 6, lane = tid & 63;
  int tileid = wid & 1, kh = wid >> 1;      // kh 0..3 (64 ch each)
  int l15 = lane & 15, g = lane >> 4;
  int pixl = tileid * 16 + l15;
  int pix = px0 + pixl;

  floatx4 acc[4];
#pragma unroll
  for (int ot = 0; ot < 4; ++ot) acc[ot] = (floatx4){0.f, 0.f, 0.f, 0.f};

  const unsigned short* ab = Aw1 + l15 * 32 + g * 8;

#pragma unroll
  for (int s = 0; s < 2; ++s) {
    int ks = kh * 2 + s;
    int c0k = ks * 32 + g * 8;
    short8v bfrag = *(const short8v*)(xs + pixl * 264 + c0k);
#pragma unroll
    for (int ot = 0; ot < 4; ++ot) {
      short8v af = *(const short8v*)(ab + (ks * 64 + ot * 16) * 32);
      acc[ot] = __builtin_amdgcn_mfma_f32_16x16x32_bf16(af, bfrag, acc[ot], 0, 0, 0);
    }
  }

  if (kh > 0) {
#pragma unroll
    for (int ot = 0; ot < 4; ++ot)
#pragma unroll
      for (int r = 0; r < 4; ++r)
        pacc[tileid][lane][(kh - 1) * 16 + ot * 4 + r] = acc[ot][r];
  }
  __syncthreads();
  if (kh == 0) {
    unsigned short* cp = comp_cl + ((size_t)(n * HW + pix)) * 64;
#pragma unroll
    for (int ot = 0; ot < 4; ++ot) {
      const float4 bv = *(const float4*)(b_comp + ot * 16 + g * 4);
      float v0 = acc[ot][0] + bv.x, v1 = acc[ot][1] + bv.y;
      float v2 = acc[ot][2] + bv.z, v3 = acc[ot][3] + bv.w;
#pragma unroll
      for (int sl = 0; sl < 3; ++sl) {
        v0 += pacc[tileid][lane][sl * 16 + ot * 4 + 0];
        v1 += pacc[tileid][lane][sl * 16 + ot * 4 + 1];
        v2 += pacc[tileid][lane][sl * 16 + ot * 4 + 2];
        v3 += pacc[tileid][lane][sl * 16 + ot * 4 + 3];
      }
      unsigned h01 = (unsigned)f2bf(v0) | ((unsigned)f2bf(v1) << 16);
      unsigned h23 = (unsigned)f2bf(v2) | ((unsigned)f2bf(v3) << 16);
      *(int2*)(cp + ot * 16 + g * 4) = make_int2((int)h01, (int)h23);
    }
  }
}

// ---------------------------------------------------------------------------
// Kernel 2: 3x3 conv + pixel-shuffle + softmax(25), K-split 4 (unchanged).
// ---------------------------------------------------------------------------
__global__ __launch_bounds__(512, 1) void kenc_mfma(
    const unsigned short* __restrict__ comp_cl,
    const unsigned short* __restrict__ Aw2,
    const float* __restrict__ b_enc, unsigned int* __restrict__ wpack) {
  __shared__ float pacc[2][64][85];
  int tid = threadIdx.x;
  int wid = tid >> 6, lane = tid & 63;
  int tileid = wid & 1, kh = wid >> 1;    // kh 0..3
  int Nt = blockIdx.x * 2 + tileid;       // 0..1023
  int n = Nt >> 8, pixbase = (Nt & 255) * 16;
  int l15 = lane & 15, g = lane >> 4;
  int pix = pixbase + l15;
  int y = pix >> 6, xcol = pix & 63;

  bool vm[9];
  int sh9[9];
#pragma unroll
  for (int t = 0; t < 9; ++t) {
    int dy = t / 3, dx = t % 3;
    vm[t] = ((unsigned)(y + dy - 1) < 64u) && ((unsigned)(xcol + dx - 1) < 64u);
    sh9[t] = (dy - 1) * 64 + (dx - 1);
  }

  floatx4 acc[7];
#pragma unroll
  for (int ot = 0; ot < 7; ++ot) acc[ot] = (floatx4){0.f, 0.f, 0.f, 0.f};

  const unsigned short* cb = comp_cl + (size_t)n * HW * 64;
  const unsigned short* ab = Aw2 + l15 * 32 + g * 8;
  const short8v zv = {0, 0, 0, 0, 0, 0, 0, 0};

  int ks0 = (kh < 2) ? kh * 5 : 10 + (kh - 2) * 4;
  int len = (kh < 2) ? 5 : 4;
#pragma unroll
  for (int s = 0; s < 5; ++s) {
    if (s < len) {
      int ks = ks0 + s;
      int t = ks >> 1, mh = ks & 1;
      const unsigned short* bp = cb + (pix + sh9[t]) * 64 + mh * 32 + g * 8;
      short8v bfrag = vm[t] ? *(const short8v*)bp : zv;
#pragma unroll
      for (int ot = 0; ot < 7; ++ot) {
        short8v af = *(const short8v*)(ab + (ks * 112 + ot * 16) * 32);
        acc[ot] = __builtin_amdgcn_mfma_f32_16x16x32_bf16(af, bfrag, acc[ot], 0, 0, 0);
      }
    }
  }

  if (kh > 0) {
#pragma unroll
    for (int ot = 0; ot < 7; ++ot)
#pragma unroll
      for (int r = 0; r < 4; ++r)
        pacc[tileid][lane][(kh - 1) * 28 + ot * 4 + r] = acc[ot][r];
  }
  __syncthreads();
  if (kh == 0) {
#pragma unroll
    for (int ot = 0; ot < 7; ++ot) {
      int ob = ot * 16 + g * 4; if (ob > 96) ob = 96;
      const float4 bv = *(const float4*)(b_enc + ob);
      acc[ot][0] += bv.x; acc[ot][1] += bv.y;
      acc[ot][2] += bv.z; acc[ot][3] += bv.w;
#pragma unroll
      for (int sl = 0; sl < 3; ++sl) {
        acc[ot][0] += pacc[tileid][lane][sl * 28 + ot * 4 + 0];
        acc[ot][1] += pacc[tileid][lane][sl * 28 + ot * 4 + 1];
        acc[ot][2] += pacc[tileid][lane][sl * 28 + ot * 4 + 2];
        acc[ot][3] += pacc[tileid][lane][sl * 28 + ot * 4 + 3];
      }
    }

#pragma unroll
    for (int r = 0; r < 4; ++r) {
      float m = acc[0][r];
#pragma unroll
      for (int ot = 1; ot < 6; ++ot) m = fmaxf(m, acc[ot][r]);
      if (g == 0) m = fmaxf(m, acc[6][r]);
      m = fmaxf(m, __shfl_xor(m, 16));
      m = fmaxf(m, __shfl_xor(m, 32));
      float s = 0.f;
      float e[7];
#pragma unroll
      for (int ot = 0; ot < 7; ++ot) {
        bool val = (ot < 6) || (g == 0);
        e[ot] = val ? __expf(acc[ot][r] - m) : 0.f;
        s += e[ot];
      }
      s += __shfl_xor(s, 16);
      s += __shfl_xor(s, 32);
      float inv = 1.f / s;
#pragma unroll
      for (int ot = 0; ot < 7; ++ot) acc[ot][r] = e[ot] * inv;
    }

#pragma unroll
    for (int sh = 0; sh < 2; ++sh) {
      unsigned int* wq = wpack + ((size_t)((n * 2 + sh) * HW) + pix) * 28;
#pragma unroll
      for (int ot = 0; ot < 7; ++ot) {
        if ((ot < 6) || (g == 0)) {
          __half2 h2 = __floats2half2_rn(acc[ot][2 * sh], acc[ot][2 * sh + 1]);
          wq[ot * 4 + g] = *reinterpret_cast<unsigned int*>(&h2);
        }
      }
    }
  }
}

// ---------------------------------------------------------------------------
// Kernel 3: reassembly v10 = v9 + LDS-staged weights (kills the 4x redundant
// 224 B/thread global wpack reads: 117 MB -> 14.7 MB) + branchless edge
// staging. LDS 30.7 KB patch + 7.2 KB weights = 37.9 KB -> 4 blocks/CU.
// ---------------------------------------------------------------------------
#define TAP4(W, V, fv)                                                         \
  asm("v_fma_mix_f32 %0, %1, %2, %0 op_sel:[0,0,0] op_sel_hi:[1,0,0]"          \
      : "+v"(a00) : "v"(W), "v"(fv));                                          \
  asm("v_fma_mix_f32 %0, %1, %2, %0 op_sel:[1,0,0] op_sel_hi:[1,0,0]"          \
      : "+v"(a01) : "v"(W), "v"(fv));                                          \
  asm("v_fma_mix_f32 %0, %1, %2, %0 op_sel:[0,0,0] op_sel_hi:[1,0,0]"          \
      : "+v"(a10) : "v"(V), "v"(fv));                                          \
  asm("v_fma_mix_f32 %0, %1, %2, %0 op_sel:[1,0,0] op_sel_hi:[1,0,0]"          \
      : "+v"(a11) : "v"(V), "v"(fv));

#define ROW5(WA, WB, WC, WD, WE, VA, VB, VC, VD, VE, RP)                       \
  { const float* rr = (RP);                                                    \
    float g0 = rr[0], g1 = rr[1], g2 = rr[2], g3 = rr[3], g4 = rr[4];          \
    TAP4(WA, VA, g0) TAP4(WB, VB, g1) TAP4(WC, VC, g2)                         \
    TAP4(WD, VD, g3) TAP4(WE, VE, g4) }

__device__ __forceinline__ float4 load_slot20(const float* __restrict__ xb,
                                              int h0, int w0, int f,
                                              bool interior) {
  int c = f / 30, rem = f - c * 30, r = rem / 5, h = rem - r * 5;
  int gh = h0 - 2 + r, gw = w0 - 2 + h * 4;
  if (interior) {
    const float* gp = xb + (size_t)c * HW + gh * WW + gw;
    float2 lo = *(const float2*)gp;       // gw even -> 8B aligned
    float2 hi = *(const float2*)(gp + 2);
    return make_float4(lo.x, lo.y, hi.x, hi.y);
  }
  // branchless: clamped loads + select
  int ghc = min(max(gh, 0), 63);
  const float* rowp = xb + (size_t)c * HW + ghc * WW;
  float v0 = rowp[min(max(gw + 0, 0), 63)];
  float v1 = rowp[min(max(gw + 1, 0), 63)];
  float v2 = rowp[min(max(gw + 2, 0), 63)];
  float v3 = rowp[min(max(gw + 3, 0), 63)];
  bool rok = ((unsigned)gh < 64u);
  v0 = (rok && (unsigned)(gw + 0) < 64u) ? v0 : 0.f;
  v1 = (rok && (unsigned)(gw + 1) < 64u) ? v1 : 0.f;
  v2 = (rok && (unsigned)(gw + 2) < 64u) ? v2 : 0.f;
  v3 = (rok && (unsigned)(gw + 3) < 64u) ? v3 : 0.f;
  return make_float4(v0, v1, v2, v3);
}

__global__ __launch_bounds__(256, 4) void reassembly_kernel(
    const float* __restrict__ x, const unsigned int* __restrict__ wpack,
    float* __restrict__ out) {
  __shared__ float xp[64 * 120];        // [c][r:6][col:20], dword = 4*slot
  __shared__ unsigned int wlds[1792];   // [sh:2][py:2][px:16][28]
  int tid = threadIdx.x;
  int bid = blockIdx.x;                 // tile(128) | n(4) | cg(4)
  int tile = bid & 127;
  int n = (bid >> 7) & 3;
  int cg = bid >> 9;                    // 64-channel group
  int tyi = tile >> 2, txi = tile & 3;  // 32 x 4 tiles of 4x32 outputs
  int ty0 = tyi * 4, tx0 = txi * 32;
  int h0 = ty0 >> 1, w0 = tx0 >> 1;     // input core base (2 rows x 16 cols)

  const float* xb = x + (size_t)(n * CI + cg * 64) * HW;
  bool interior = (tyi >= 1) && (tyi <= 30) && (txi >= 1) && (txi <= 2);

  // ---- x stage loads (HBM, issue first)
  float4 s0 = load_slot20(xb, h0, w0, tid,        interior);
  float4 s1 = load_slot20(xb, h0, w0, tid + 256,  interior);
  float4 s2 = load_slot20(xb, h0, w0, tid + 512,  interior);
  float4 s3 = load_slot20(xb, h0, w0, tid + 768,  interior);
  float4 s4 = load_slot20(xb, h0, w0, tid + 1024, interior);
  float4 s5 = load_slot20(xb, h0, w0, tid + 1280, interior);
  float4 s6 = load_slot20(xb, h0, w0, tid + 1536, interior);
  bool half = tid < 128;
  float4 s7 = half ? load_slot20(xb, h0, w0, tid + 1792, interior)
                   : make_float4(0.f, 0.f, 0.f, 0.f);

  // ---- weight stage loads (L2): 1792 dwords coalesced, 7 per thread
  unsigned int g0, g1, g2, g3, g4, g5, g6;
  {
    int L0 = tid;
#pragma unroll
    for (int rr = 0; rr < 7; ++rr) {
      int L = L0 + rr * 256;
      int sh = L / 896, rem = L - sh * 896;
      int py = rem / 448, rem2 = rem - py * 448;   // px*28+k
      size_t gaddr =
          ((size_t)((n * 2 + sh) * HW) + (h0 + py) * 64 + w0) * 28 + rem2;
      unsigned int v = wpack[gaddr];
      if (rr == 0) g0 = v; else if (rr == 1) g1 = v; else if (rr == 2) g2 = v;
      else if (rr == 3) g3 = v; else if (rr == 4) g4 = v; else if (rr == 5) g5 = v;
      else g6 = v;
    }
  }

  // ---- LDS writes
  *(float4*)(xp + 4 * (tid))        = s0;
  *(float4*)(xp + 4 * (tid + 256))  = s1;
  *(float4*)(xp + 4 * (tid + 512))  = s2;
  *(float4*)(xp + 4 * (tid + 768))  = s3;
  *(float4*)(xp + 4 * (tid + 1024)) = s4;
  *(float4*)(xp + 4 * (tid + 1280)) = s5;
  *(float4*)(xp + 4 * (tid + 1536)) = s6;
  if (half) *(float4*)(xp + 4 * (tid + 1792)) = s7;
  wlds[tid]        = g0;
  wlds[tid + 256]  = g1;
  wlds[tid + 512]  = g2;
  wlds[tid + 768]  = g3;
  wlds[tid + 1024] = g4;
  wlds[tid + 1280] = g5;
  wlds[tid + 1536] = g6;

  // ---- thread mapping
  int cslot = tid >> 5;                 // 0..7
  int ip = tid & 31;                    // py(1b) | px(4b)
  int py = ip >> 4, px = ip & 15;
  int oy0 = ty0 + py * 2, ox0 = tx0 + px * 2;

  __syncthreads();

  // ---- weights from LDS into named uint4s (scratch-free)
  const unsigned int* wt0 = wlds + py * 448 + px * 28;        // sh = 0
  const unsigned int* wt1 = wt0 + 896;                        // sh = 1
  uint4 A0 = *(const uint4*)(wt0 + 0);
  uint4 A1 = *(const uint4*)(wt0 + 4);
  uint4 A2 = *(const uint4*)(wt0 + 8);
  uint4 A3 = *(const uint4*)(wt0 + 12);
  uint4 A4 = *(const uint4*)(wt0 + 16);
  uint4 A5 = *(const uint4*)(wt0 + 20);
  unsigned int A6 = wt0[24];
  uint4 B0 = *(const uint4*)(wt1 + 0);
  uint4 B1 = *(const uint4*)(wt1 + 4);
  uint4 B2 = *(const uint4*)(wt1 + 8);
  uint4 B3 = *(const uint4*)(wt1 + 12);
  uint4 B4 = *(const uint4*)(wt1 + 16);
  uint4 B5 = *(const uint4*)(wt1 + 20);
  unsigned int B6 = wt1[24];

  // ---- compute: 8 channel-iters, 2x2 output quad per iter
  float* outb = out + ((size_t)(n * CI + cg * 64) * HS + oy0) * WS_ + ox0;
  for (int it = 0; it < 8; ++it) {
    int cl = it * 8 + cslot;
    const float* p = xp + cl * 120 + py * 20 + px;
    float a00 = 0.f, a01 = 0.f, a10 = 0.f, a11 = 0.f;
    ROW5(A0.x, A0.y, A0.z, A0.w, A1.x, B0.x, B0.y, B0.z, B0.w, B1.x, p)
    ROW5(A1.y, A1.z, A1.w, A2.x, A2.y, B1.y, B1.z, B1.w, B2.x, B2.y, p + 20)
    ROW5(A2.z, A2.w, A3.x, A3.y, A3.z, B2.z, B2.w, B3.x, B3.y, B3.z, p + 40)
    ROW5(A3.w, A4.x, A4.y, A4.z, A4.w, B3.w, B4.x, B4.y, B4.z, B4.w, p + 60)
    ROW5(A5.x, A5.y, A5.z, A5.w, A6,   B5.x, B5.y, B5.z, B5.w, B6,   p + 80)
    float* ob = outb + (size_t)cl * HS * WS_;
    *(float2*)(ob)       = make_float2(a00, a01);
    *(float2*)(ob + WS_) = make_float2(a10, a11);
  }
}

// ---------------------------------------------------------------------------
extern "C" void kernel_launch(void* const* d_in, const int* in_sizes, int n_in,
                              void* d_out, int out_size, void* d_ws,
                              size_t ws_size, hipStream_t stream) {
  const float* x      = (const float*)d_in[0];
  const float* w_comp = (const float*)d_in[1];
  const float* b_comp = (const float*)d_in[2];
  const float* w_enc  = (const float*)d_in[3];
  const float* b_enc  = (const float*)d_in[4];
  float* out = (float*)d_out;

  char* ws = (char*)d_ws;
  unsigned short* comp_cl = (unsigned short*)ws;                  // 2,097,152 B
  unsigned short* Aw1     = (unsigned short*)(ws + 2097152);      //    32,768 B
  unsigned short* Aw2     = (unsigned short*)(ws + 2129920);      //   129,024 B
  unsigned int*   wpack   = (unsigned int*)(ws + 2359296);        // 3,670,016 B

  prep_kernel<<<dim3(316), 256, 0, stream>>>(w_comp, w_enc, Aw1, Aw2);
  conv1x1_mfma<<<dim3(512), 512, 0, stream>>>(x, Aw1, b_comp, comp_cl);
  kenc_mfma<<<dim3(512), 512, 0, stream>>>(comp_cl, Aw2, b_enc, wpack);
  reassembly_kernel<<<dim3(2048), 256, 0, stream>>>(x, wpack, out);
}

// Round 12
// 57.288 us; speedup vs baseline: 1.1678x; 1.1678x over previous
//
#include <hip/hip_runtime.h>
#include <hip/hip_fp16.h>

// Problem constants
#define NB 4      // batch
#define CI 256    // input channels
#define HH 64
#define WW 64
#define MC 64     // compressed channels
#define HS 128    // H*2
#define WS_ 128   // W*2
#define HW 4096   // HH*WW

typedef __attribute__((ext_vector_type(8))) short short8v;   // 8 bf16 (4 VGPRs)
typedef __attribute__((ext_vector_type(4))) float floatx4;   // MFMA C/D

__device__ inline unsigned short f2bf(float f) {
  union { float f; unsigned u; } v; v.f = f;
  unsigned r = v.u + 0x7FFFu + ((v.u >> 16) & 1u);   // RNE
  return (unsigned short)(r >> 16);
}

// ---------------------------------------------------------------------------
// Prep: rearrange weights into MFMA A-fragment layout (bf16).  (unchanged)
// ---------------------------------------------------------------------------
__global__ __launch_bounds__(256) void prep_kernel(
    const float* __restrict__ w_comp, const float* __restrict__ w_enc,
    unsigned short* __restrict__ Aw1, unsigned short* __restrict__ Aw2) {
  int i = blockIdx.x * 256 + threadIdx.x;
  if (i < 16384) {                       // 8*64*32
    int kl = i & 31, o = (i >> 5) & 63, ks = i >> 11;
    Aw1[i] = f2bf(w_comp[o * 256 + ks * 32 + kl]);
  } else if (i < 16384 + 64512) {        // 18*112*32
    int j = i - 16384;
    int kl = j & 31, o = (j >> 5) % 112, ks = (j >> 5) / 112;
    int t = ks >> 1, m = (ks & 1) * 32 + kl;
    Aw2[j] = (o < 100) ? f2bf(w_enc[o * 576 + m * 9 + t]) : (unsigned short)0;
  }
}

// ---------------------------------------------------------------------------
// Kernel 1: 1x1 conv via MFMA, K-split 4 (round-10 version, best total).
// ---------------------------------------------------------------------------
__global__ __launch_bounds__(512, 1) void conv1x1_mfma(
    const float* __restrict__ x, const unsigned short* __restrict__ Aw1,
    const float* __restrict__ b_comp, unsigned short* __restrict__ comp_cl) {
  __shared__ float pacc[2][64][49];
  int tid = threadIdx.x;
  int wid = tid >> 6, lane = tid & 63;
  int tileid = wid & 1, kh = wid >> 1;    // kh 0..3
  int Nt = blockIdx.x * 2 + tileid;       // 0..1023
  int n = Nt >> 8, pixbase = (Nt & 255) * 16;
  int l15 = lane & 15, g = lane >> 4;
  int pix = pixbase + l15;

  floatx4 acc[4];
#pragma unroll
  for (int ot = 0; ot < 4; ++ot) acc[ot] = (floatx4){0.f, 0.f, 0.f, 0.f};

  const float* xb = x + (size_t)n * CI * HW + pix;
  const unsigned short* ab = Aw1 + l15 * 32 + g * 8;

#pragma unroll
  for (int s = 0; s < 2; ++s) {
    int ks = kh * 2 + s;
    int c0 = ks * 32 + g * 8;
    short8v bfrag;
#pragma unroll
    for (int j = 0; j < 8; ++j)
      bfrag[j] = (short)f2bf(xb[(size_t)(c0 + j) * HW]);
#pragma unroll
    for (int ot = 0; ot < 4; ++ot) {
      short8v af = *(const short8v*)(ab + (ks * 64 + ot * 16) * 32);
      acc[ot] = __builtin_amdgcn_mfma_f32_16x16x32_bf16(af, bfrag, acc[ot], 0, 0, 0);
    }
  }

  if (kh > 0) {
#pragma unroll
    for (int ot = 0; ot < 4; ++ot)
#pragma unroll
      for (int r = 0; r < 4; ++r)
        pacc[tileid][lane][(kh - 1) * 16 + ot * 4 + r] = acc[ot][r];
  }
  __syncthreads();
  if (kh == 0) {
    unsigned short* cp = comp_cl + ((size_t)(n * HW + pix)) * 64;
#pragma unroll
    for (int ot = 0; ot < 4; ++ot) {
      const float4 bv = *(const float4*)(b_comp + ot * 16 + g * 4);
      float v0 = acc[ot][0] + bv.x, v1 = acc[ot][1] + bv.y;
      float v2 = acc[ot][2] + bv.z, v3 = acc[ot][3] + bv.w;
#pragma unroll
      for (int sl = 0; sl < 3; ++sl) {
        v0 += pacc[tileid][lane][sl * 16 + ot * 4 + 0];
        v1 += pacc[tileid][lane][sl * 16 + ot * 4 + 1];
        v2 += pacc[tileid][lane][sl * 16 + ot * 4 + 2];
        v3 += pacc[tileid][lane][sl * 16 + ot * 4 + 3];
      }
      unsigned h01 = (unsigned)f2bf(v0) | ((unsigned)f2bf(v1) << 16);
      unsigned h23 = (unsigned)f2bf(v2) | ((unsigned)f2bf(v3) << 16);
      *(int2*)(cp + ot * 16 + g * 4) = make_int2((int)h01, (int)h23);
    }
  }
}

// ---------------------------------------------------------------------------
// Kernel 2 (FUSED): kenc (3x3 conv + pixel-shuffle + softmax(25)) for this
// tile's 2x16 input px -> packed-f16 weights in LDS -> reassembly over all
// 256 channels in 4 stages of 64.
// Block = 512 thr; tile = 4x32 outputs (2x16 input core).  LDS 50.7 KB
// (pacc 43.5 KB phase-1 UNION xp 30.7 KB phase-2, + wlds 7.2 KB) ->
// 3 blocks/CU.  Weights never touch global memory.
// ---------------------------------------------------------------------------
#define TAP4(W, V, fv)                                                         \
  asm("v_fma_mix_f32 %0, %1, %2, %0 op_sel:[0,0,0] op_sel_hi:[1,0,0]"          \
      : "+v"(a00) : "v"(W), "v"(fv));                                          \
  asm("v_fma_mix_f32 %0, %1, %2, %0 op_sel:[1,0,0] op_sel_hi:[1,0,0]"          \
      : "+v"(a01) : "v"(W), "v"(fv));                                          \
  asm("v_fma_mix_f32 %0, %1, %2, %0 op_sel:[0,0,0] op_sel_hi:[1,0,0]"          \
      : "+v"(a10) : "v"(V), "v"(fv));                                          \
  asm("v_fma_mix_f32 %0, %1, %2, %0 op_sel:[1,0,0] op_sel_hi:[1,0,0]"          \
      : "+v"(a11) : "v"(V), "v"(fv));

#define ROW5(WA, WB, WC, WD, WE, VA, VB, VC, VD, VE, RP)                       \
  { const float* rr = (RP);                                                    \
    float g0 = rr[0], g1 = rr[1], g2 = rr[2], g3 = rr[3], g4 = rr[4];          \
    TAP4(WA, VA, g0) TAP4(WB, VB, g1) TAP4(WC, VC, g2)                         \
    TAP4(WD, VD, g3) TAP4(WE, VE, g4) }

__device__ __forceinline__ float4 load_slot20(const float* __restrict__ xb,
                                              int h0, int w0, int f,
                                              bool interior) {
  int c = f / 30, rem = f - c * 30, r = rem / 5, h = rem - r * 5;
  int gh = h0 - 2 + r, gw = w0 - 2 + h * 4;
  if (interior) {
    const float* gp = xb + (size_t)c * HW + gh * WW + gw;
    float2 lo = *(const float2*)gp;       // gw even -> 8B aligned
    float2 hi = *(const float2*)(gp + 2);
    return make_float4(lo.x, lo.y, hi.x, hi.y);
  }
  int ghc = min(max(gh, 0), 63);
  const float* rowp = xb + (size_t)c * HW + ghc * WW;
  float v0 = rowp[min(max(gw + 0, 0), 63)];
  float v1 = rowp[min(max(gw + 1, 0), 63)];
  float v2 = rowp[min(max(gw + 2, 0), 63)];
  float v3 = rowp[min(max(gw + 3, 0), 63)];
  bool rok = ((unsigned)gh < 64u);
  v0 = (rok && (unsigned)(gw + 0) < 64u) ? v0 : 0.f;
  v1 = (rok && (unsigned)(gw + 1) < 64u) ? v1 : 0.f;
  v2 = (rok && (unsigned)(gw + 2) < 64u) ? v2 : 0.f;
  v3 = (rok && (unsigned)(gw + 3) < 64u) ? v3 : 0.f;
  return make_float4(v0, v1, v2, v3);
}

__global__ __launch_bounds__(512, 4) void fused_kernel(
    const float* __restrict__ x,
    const unsigned short* __restrict__ comp_cl,
    const unsigned short* __restrict__ Aw2,
    const float* __restrict__ b_enc,
    float* __restrict__ out) {
  __shared__ float smem[12672];                 // 50,688 B
  float* paccF = smem;                          // phase 1: [2][64][85]
  float* xp = smem;                             // phase 2: [64][120]
  unsigned int* wlds = (unsigned int*)(smem + 10880);   // [2][2][16][28]

  int tid = threadIdx.x;
  int bid = blockIdx.x;                 // tile(128) | n(4)
  int tile = bid & 127, n = bid >> 7;
  int tyi = tile >> 2, txi = tile & 3;  // 32 x 4 tiles of 4x32 outputs
  int ty0 = tyi * 4, tx0 = txi * 32;
  int h0 = tyi * 2, w0 = txi * 16;      // input core base (2 rows x 16 cols)

  int wid = tid >> 6, lane = tid & 63;
  int tileid = wid & 1, kh = wid >> 1;  // row-wave, K-quarter
  int l15 = lane & 15, g = lane >> 4;

  // ================= phase 1: kenc for the 2x16 core px ====================
  {
    int pix = (h0 + tileid) * 64 + w0 + l15;
    int y = pix >> 6, xcol = pix & 63;

    bool vm[9];
    int sh9[9];
#pragma unroll
    for (int t = 0; t < 9; ++t) {
      int dy = t / 3, dx = t % 3;
      vm[t] = ((unsigned)(y + dy - 1) < 64u) && ((unsigned)(xcol + dx - 1) < 64u);
      sh9[t] = (dy - 1) * 64 + (dx - 1);
    }

    floatx4 acc[7];
#pragma unroll
    for (int ot = 0; ot < 7; ++ot) acc[ot] = (floatx4){0.f, 0.f, 0.f, 0.f};

    const unsigned short* cb = comp_cl + (size_t)n * HW * 64;
    const unsigned short* ab = Aw2 + l15 * 32 + g * 8;
    const short8v zv = {0, 0, 0, 0, 0, 0, 0, 0};

    int ks0 = (kh < 2) ? kh * 5 : 10 + (kh - 2) * 4;
    int len = (kh < 2) ? 5 : 4;
#pragma unroll
    for (int s = 0; s < 5; ++s) {
      if (s < len) {
        int ks = ks0 + s;
        int t = ks >> 1, mh = ks & 1;
        const unsigned short* bp = cb + (pix + sh9[t]) * 64 + mh * 32 + g * 8;
        short8v bfrag = vm[t] ? *(const short8v*)bp : zv;
#pragma unroll
        for (int ot = 0; ot < 7; ++ot) {
          short8v af = *(const short8v*)(ab + (ks * 112 + ot * 16) * 32);
          acc[ot] = __builtin_amdgcn_mfma_f32_16x16x32_bf16(af, bfrag, acc[ot], 0, 0, 0);
        }
      }
    }

    if (kh > 0) {
#pragma unroll
      for (int ot = 0; ot < 7; ++ot)
#pragma unroll
        for (int r = 0; r < 4; ++r)
          paccF[(tileid * 64 + lane) * 85 + (kh - 1) * 28 + ot * 4 + r] =
              acc[ot][r];
    }
    __syncthreads();
    if (kh == 0) {
#pragma unroll
      for (int ot = 0; ot < 7; ++ot) {
        int ob = ot * 16 + g * 4; if (ob > 96) ob = 96;
        const float4 bv = *(const float4*)(b_enc + ob);
        acc[ot][0] += bv.x; acc[ot][1] += bv.y;
        acc[ot][2] += bv.z; acc[ot][3] += bv.w;
#pragma unroll
        for (int sl = 0; sl < 3; ++sl) {
          acc[ot][0] += paccF[(tileid * 64 + lane) * 85 + sl * 28 + ot * 4 + 0];
          acc[ot][1] += paccF[(tileid * 64 + lane) * 85 + sl * 28 + ot * 4 + 1];
          acc[ot][2] += paccF[(tileid * 64 + lane) * 85 + sl * 28 + ot * 4 + 2];
          acc[ot][3] += paccF[(tileid * 64 + lane) * 85 + sl * 28 + ot * 4 + 3];
        }
      }

      // per-r softmax; normalized values back into acc[ot][r]
#pragma unroll
      for (int r = 0; r < 4; ++r) {
        float m = acc[0][r];
#pragma unroll
        for (int ot = 1; ot < 6; ++ot) m = fmaxf(m, acc[ot][r]);
        if (g == 0) m = fmaxf(m, acc[6][r]);
        m = fmaxf(m, __shfl_xor(m, 16));
        m = fmaxf(m, __shfl_xor(m, 32));
        float s = 0.f;
        float e[7];
#pragma unroll
        for (int ot = 0; ot < 7; ++ot) {
          bool val = (ot < 6) || (g == 0);
          e[ot] = val ? __expf(acc[ot][r] - m) : 0.f;
          s += e[ot];
        }
        s += __shfl_xor(s, 16);
        s += __shfl_xor(s, 32);
        float inv = 1.f / s;
#pragma unroll
        for (int ot = 0; ot < 7; ++ot) acc[ot][r] = e[ot] * inv;
      }

      // pack f16 pairs into LDS: wlds[sh][row=tileid][px=l15][k=ot*4+g]
#pragma unroll
      for (int sh = 0; sh < 2; ++sh) {
        unsigned int* wq = wlds + sh * 896 + tileid * 448 + l15 * 28;
#pragma unroll
        for (int ot = 0; ot < 7; ++ot) {
          if ((ot < 6) || (g == 0)) {
            __half2 h2 = __floats2half2_rn(acc[ot][2 * sh], acc[ot][2 * sh + 1]);
            wq[ot * 4 + g] = *reinterpret_cast<unsigned int*>(&h2);
          }
        }
      }
    }
  }
  __syncthreads();   // wlds complete; paccF dead

  // ================= phase 2: reassembly, 4 stages of 64 channels ==========
  int cslot = tid >> 5;                 // 0..15
  int ip = tid & 31;                    // py(1b) | px(4b)
  int py = ip >> 4, px = ip & 15;
  int oy0 = ty0 + py * 2, ox0 = tx0 + px * 2;

  // weights from LDS into named uint4s (112 B offsets are 16B-aligned)
  const unsigned int* wt0 = wlds + py * 448 + px * 28;        // sh = 0
  const unsigned int* wt1 = wt0 + 896;                        // sh = 1
  uint4 A0 = *(const uint4*)(wt0 + 0);
  uint4 A1 = *(const uint4*)(wt0 + 4);
  uint4 A2 = *(const uint4*)(wt0 + 8);
  uint4 A3 = *(const uint4*)(wt0 + 12);
  uint4 A4 = *(const uint4*)(wt0 + 16);
  uint4 A5 = *(const uint4*)(wt0 + 20);
  unsigned int A6 = wt0[24];
  uint4 B0 = *(const uint4*)(wt1 + 0);
  uint4 B1 = *(const uint4*)(wt1 + 4);
  uint4 B2 = *(const uint4*)(wt1 + 8);
  uint4 B3 = *(const uint4*)(wt1 + 12);
  uint4 B4 = *(const uint4*)(wt1 + 16);
  uint4 B5 = *(const uint4*)(wt1 + 20);
  unsigned int B6 = wt1[24];

  bool interior = (tyi >= 1) && (tyi <= 30) && (txi >= 1) && (txi <= 2);
  bool extra = tid < 384;

  for (int cs = 0; cs < 4; ++cs) {
    const float* xb = x + (size_t)(n * CI + cs * 64) * HW;
    // stage 64 ch x 6x20 halo: 1920 f4 slots, 3.75 per thread
    float4 s0 = load_slot20(xb, h0, w0, tid,        interior);
    float4 s1 = load_slot20(xb, h0, w0, tid + 512,  interior);
    float4 s2 = load_slot20(xb, h0, w0, tid + 1024, interior);
    float4 s3 = extra ? load_slot20(xb, h0, w0, tid + 1536, interior)
                      : make_float4(0.f, 0.f, 0.f, 0.f);
    if (cs > 0) __syncthreads();        // prior compute done before overwrite
    *(float4*)(xp + 4 * (tid))        = s0;
    *(float4*)(xp + 4 * (tid + 512))  = s1;
    *(float4*)(xp + 4 * (tid + 1024)) = s2;
    if (extra) *(float4*)(xp + 4 * (tid + 1536)) = s3;
    __syncthreads();

    float* outb = out + ((size_t)(n * CI + cs * 64) * HS + oy0) * WS_ + ox0;
#pragma unroll
    for (int it = 0; it < 4; ++it) {
      int cl = it * 16 + cslot;
      const float* p = xp + cl * 120 + py * 20 + px;
      float a00 = 0.f, a01 = 0.f, a10 = 0.f, a11 = 0.f;
      ROW5(A0.x, A0.y, A0.z, A0.w, A1.x, B0.x, B0.y, B0.z, B0.w, B1.x, p)
      ROW5(A1.y, A1.z, A1.w, A2.x, A2.y, B1.y, B1.z, B1.w, B2.x, B2.y, p + 20)
      ROW5(A2.z, A2.w, A3.x, A3.y, A3.z, B2.z, B2.w, B3.x, B3.y, B3.z, p + 40)
      ROW5(A3.w, A4.x, A4.y, A4.z, A4.w, B3.w, B4.x, B4.y, B4.z, B4.w, p + 60)
      ROW5(A5.x, A5.y, A5.z, A5.w, A6,   B5.x, B5.y, B5.z, B5.w, B6,   p + 80)
      float* ob = outb + (size_t)cl * HS * WS_;
      *(float2*)(ob)       = make_float2(a00, a01);
      *(float2*)(ob + WS_) = make_float2(a10, a11);
    }
  }
}

// ---------------------------------------------------------------------------
extern "C" void kernel_launch(void* const* d_in, const int* in_sizes, int n_in,
                              void* d_out, int out_size, void* d_ws,
                              size_t ws_size, hipStream_t stream) {
  const float* x      = (const float*)d_in[0];
  const float* w_comp = (const float*)d_in[1];
  const float* b_comp = (const float*)d_in[2];
  const float* w_enc  = (const float*)d_in[3];
  const float* b_enc  = (const float*)d_in[4];
  float* out = (float*)d_out;

  char* ws = (char*)d_ws;
  unsigned short* comp_cl = (unsigned short*)ws;                  // 2,097,152 B
  unsigned short* Aw1     = (unsigned short*)(ws + 2097152);      //    32,768 B
  unsigned short* Aw2     = (unsigned short*)(ws + 2129920);      //   129,024 B

  prep_kernel<<<dim3(316), 256, 0, stream>>>(w_comp, w_enc, Aw1, Aw2);
  conv1x1_mfma<<<dim3(512), 512, 0, stream>>>(x, Aw1, b_comp, comp_cl);
  fused_kernel<<<dim3(512), 512, 0, stream>>>(x, comp_cl, Aw2, b_enc, out);
}